// Round 2
// 521.622 us; speedup vs baseline: 1.3823x; 1.3823x over previous
//
#include <hip/hip_runtime.h>
#include <hip/hip_bf16.h>
#include <stdint.h>

#define M_DIM 8192
#define N_DIM 4096
#define K_DIM 4096

#define BM 256
#define BN 256
#define BK 64
#define NT (K_DIM / BK)   // 64 K-tiles
#define NH (NT * 4)       // 256 half-tiles (A0,A1,B0,B1 per K-tile)

typedef __bf16 bf16x8 __attribute__((ext_vector_type(8)));
typedef float f32x4 __attribute__((ext_vector_type(4)));

// ---------------------------------------------------------------- helpers
__device__ __forceinline__ unsigned short f2bf(float f) {
  unsigned int u = __float_as_uint(f);
  u += 0x7fffu + ((u >> 16) & 1u);
  return (unsigned short)(u >> 16);
}
__device__ __forceinline__ unsigned int pack2(float lo, float hi) {
  return (unsigned int)f2bf(lo) | ((unsigned int)f2bf(hi) << 16);
}
__device__ __forceinline__ void async_copy16(const void* g, void* l) {
  __builtin_amdgcn_global_load_lds(
      (__attribute__((address_space(1))) void*)(g),
      (__attribute__((address_space(3))) void*)(l),
      16, 0, 0);
}

// ------------------------------------------------ prepass 1: A fp32->bf16
__global__ void convert_a_kernel(const float* __restrict__ in,
                                 unsigned short* __restrict__ out) {
  size_t t = (size_t)blockIdx.x * 256 + threadIdx.x;
  size_t base = t * 16;
  const float4* p = (const float4*)(in + base);
  float4 v0 = p[0], v1 = p[1], v2 = p[2], v3 = p[3];
  uint4 o0, o1;
  o0.x = pack2(v0.x, v0.y); o0.y = pack2(v0.z, v0.w);
  o0.z = pack2(v1.x, v1.y); o0.w = pack2(v1.z, v1.w);
  o1.x = pack2(v2.x, v2.y); o1.y = pack2(v2.z, v2.w);
  o1.z = pack2(v3.x, v3.y); o1.w = pack2(v3.z, v3.w);
  uint4* q = (uint4*)(out + base);
  q[0] = o0; q[1] = o1;
}

// --------------------------- prepass 2: Wt[o][i] = bf16(W[i][o]*Mask[i][o])
#define TS 72
__global__ __launch_bounds__(256) void maskT_kernel(
    const float* __restrict__ W, const float* __restrict__ Msk,
    unsigned short* __restrict__ Wt) {
  __shared__ unsigned short tile[64 * TS];
  const int t = threadIdx.x;
  const size_t i0 = (size_t)blockIdx.y * 64;
  const size_t o0 = (size_t)blockIdx.x * 64;

  const int o4 = (t & 15) * 4;
  const int i4 = (t >> 4) * 4;
  float4 w[4], m[4];
#pragma unroll
  for (int r = 0; r < 4; ++r) {
    const size_t gi = (i0 + i4 + r) * N_DIM + o0 + o4;
    w[r] = *(const float4*)(W + gi);
    m[r] = *(const float4*)(Msk + gi);
  }
  float e[4][4];
#pragma unroll
  for (int r = 0; r < 4; ++r) {
    e[r][0] = w[r].x * m[r].x; e[r][1] = w[r].y * m[r].y;
    e[r][2] = w[r].z * m[r].z; e[r][3] = w[r].w * m[r].w;
  }
#pragma unroll
  for (int c = 0; c < 4; ++c) {
    uint2 packed;
    packed.x = pack2(e[0][c], e[1][c]);
    packed.y = pack2(e[2][c], e[3][c]);
    *(uint2*)(tile + (o4 + c) * TS + i4) = packed;
  }
  __syncthreads();

  const int o_l = t >> 2;
  const int iseg = (t & 3) * 16;
  uint4 a = *(const uint4*)(tile + o_l * TS + iseg);
  uint4 b = *(const uint4*)(tile + o_l * TS + iseg + 8);
  unsigned short* dst = Wt + (o0 + o_l) * K_DIM + i0 + iseg;
  ((uint4*)dst)[0] = a;
  ((uint4*)dst)[1] = b;
}

// ------------------------------------------------ main GEMM: 256x256 8-phase
// A: bf16 [M][K]; Bt: bf16 [N][K]; C: fp32 [M][N]
// 512 threads = 8 waves (2M x 4N), per-wave output 128x64.
// LDS 128 KiB: [2 buf][A 256x64 | B 256x64] bf16, double-buffered per K-tile.
// Swizzle (rule #21): LDS linear; global SOURCE seg q = p ^ (row&7);
// ds_read applies same XOR -> 8 lanes/bank-quartet per ds_read_b128 (balanced).
// Schedule: 4 phases / K-tile, counted vmcnt(2) once per K-tile (T3+T4),
// setprio around MFMA cluster (T5), lgkmcnt(0)+sched_barrier(0) (rule #18).
// vmcnt ledger: prologue 10 issued, wait(2) -> tile0 landed. Steady state:
// 2 carried + 8 issued/tile; phase-3 wait(2) completes halves 4t+4..4t+7
// = tile t+1. Tail (t>=NT-2): wait(0), stage guards skip h>=NH.
// Race-freedom: the only stage into the read buffer is h=4t+8 (phase 3),
// issued after phase 2's end barrier which follows every wave's lgkmcnt(0)
// drain of the buffer's last ds_read.
__global__ __launch_bounds__(512, 2) void gemm_bf16_kernel(
    const unsigned short* __restrict__ A,
    const unsigned short* __restrict__ Bt,
    float* __restrict__ C) {
  __shared__ unsigned short lds[65536];  // 128 KiB

  const int tid  = threadIdx.x;
  const int wave = tid >> 6;
  const int lane = tid & 63;
  const int l16  = lane & 15;
  const int quad = lane >> 4;
  const int wm   = (wave >> 2) * 128;   // 2 M-waves
  const int wn   = (wave & 3) * 64;     // 4 N-waves

  // XCD-aware bijective swizzle: 512 blocks, 64/XCD = 2 bn-cols x 32 bm-rows
  const int flat = blockIdx.y * gridDim.x + blockIdx.x;
  const int xcd  = flat & 7;
  const int slot = flat >> 3;
  const int bx   = xcd * 2 + (slot & 1);
  const int by   = slot >> 1;
  const size_t bm = (size_t)by * BM;
  const size_t bn = (size_t)bx * BN;

  // staging: thread t covers slots t and t+512 of a 128x8 half-tile (16B slots)
  const int lr0 = tid >> 3;            // row 0..63 (second copy adds 64)
  const int p0  = tid & 7;             // physical 16B seg
  const int q0  = p0 ^ (lr0 & 7);      // pre-swizzled global seg
  const unsigned short* pa = A  + (bm + lr0) * (size_t)K_DIM + q0 * 8;
  const unsigned short* pb = Bt + (bn + lr0) * (size_t)K_DIM + q0 * 8;

  auto stage = [&](int h) {
    const int u    = h >> 2;           // K-tile
    const int hk   = h & 1;            // row half
    const int isB  = (h >> 1) & 1;     // A or B
    const int bufh = u & 1;
    const unsigned short* s =
        (isB ? pb : pa) + (size_t)(hk * 128) * K_DIM + u * 64;
    unsigned short* d =
        lds + bufh * 32768 + isB * 16384 + hk * 8192 + wave * 512;
    async_copy16(s, d);
    async_copy16(s + (size_t)64 * K_DIM, d + 4096);
  };

  const int sx = (l16 & 7) * 8;  // reader seg-XOR, in elements

  f32x4 acc[8][4] = {};
  bf16x8 afr[4][2], bfr[2][2], bfr2[2][2];

  // prologue: halves 0..4 (tile0 complete + tile1 A0), wait tile0 landed
  stage(0); stage(1); stage(2); stage(3); stage(4);
  asm volatile("s_waitcnt vmcnt(2)" ::: "memory");
  __builtin_amdgcn_s_barrier();
  asm volatile("" ::: "memory");

  for (int t = 0; t < NT; ++t) {
    const unsigned short* Ab = lds + (t & 1) * 32768;
    const unsigned short* Bb = Ab + 16384;
    const int h0 = 4 * t + 5;

    // ---------------- phase 0: read A[0..3], B[0..1]; MFMA Q(0,0)
#pragma unroll
    for (int i = 0; i < 4; ++i)
#pragma unroll
      for (int ks = 0; ks < 2; ++ks)
        afr[i][ks] = *(const bf16x8*)(Ab + (wm + i * 16 + l16) * 64 +
                                      ((ks * 32 + quad * 8) ^ sx));
#pragma unroll
    for (int j = 0; j < 2; ++j)
#pragma unroll
      for (int ks = 0; ks < 2; ++ks)
        bfr[j][ks] = *(const bf16x8*)(Bb + (wn + j * 16 + l16) * 64 +
                                      ((ks * 32 + quad * 8) ^ sx));
    if (h0 < NH) stage(h0);
    asm volatile("" ::: "memory");
    __builtin_amdgcn_s_barrier();
    asm volatile("s_waitcnt lgkmcnt(0)" ::: "memory");
    __builtin_amdgcn_sched_barrier(0);
    __builtin_amdgcn_s_setprio(1);
#pragma unroll
    for (int i = 0; i < 4; ++i)
#pragma unroll
      for (int j = 0; j < 2; ++j)
#pragma unroll
        for (int ks = 0; ks < 2; ++ks)
          acc[i][j] = __builtin_amdgcn_mfma_f32_16x16x32_bf16(
              afr[i][ks], bfr[j][ks], acc[i][j], 0, 0, 0);
    __builtin_amdgcn_sched_barrier(0);
    __builtin_amdgcn_s_setprio(0);
    asm volatile("" ::: "memory");
    __builtin_amdgcn_s_barrier();
    asm volatile("" ::: "memory");

    // ---------------- phase 1: read B[2..3]; MFMA Q(0,1)
#pragma unroll
    for (int j = 0; j < 2; ++j)
#pragma unroll
      for (int ks = 0; ks < 2; ++ks)
        bfr2[j][ks] = *(const bf16x8*)(Bb + (wn + (2 + j) * 16 + l16) * 64 +
                                       ((ks * 32 + quad * 8) ^ sx));
    if (h0 + 1 < NH) stage(h0 + 1);
    asm volatile("" ::: "memory");
    __builtin_amdgcn_s_barrier();
    asm volatile("s_waitcnt lgkmcnt(0)" ::: "memory");
    __builtin_amdgcn_sched_barrier(0);
    __builtin_amdgcn_s_setprio(1);
#pragma unroll
    for (int i = 0; i < 4; ++i)
#pragma unroll
      for (int j = 0; j < 2; ++j)
#pragma unroll
        for (int ks = 0; ks < 2; ++ks)
          acc[i][2 + j] = __builtin_amdgcn_mfma_f32_16x16x32_bf16(
              afr[i][ks], bfr2[j][ks], acc[i][2 + j], 0, 0, 0);
    __builtin_amdgcn_sched_barrier(0);
    __builtin_amdgcn_s_setprio(0);
    asm volatile("" ::: "memory");
    __builtin_amdgcn_s_barrier();
    asm volatile("" ::: "memory");

    // ---------------- phase 2: read A[4..7] (reuse afr); MFMA Q(1,0)
#pragma unroll
    for (int i = 0; i < 4; ++i)
#pragma unroll
      for (int ks = 0; ks < 2; ++ks)
        afr[i][ks] = *(const bf16x8*)(Ab + (wm + (4 + i) * 16 + l16) * 64 +
                                      ((ks * 32 + quad * 8) ^ sx));
    if (h0 + 2 < NH) stage(h0 + 2);
    asm volatile("" ::: "memory");
    __builtin_amdgcn_s_barrier();
    asm volatile("s_waitcnt lgkmcnt(0)" ::: "memory");
    __builtin_amdgcn_sched_barrier(0);
    __builtin_amdgcn_s_setprio(1);
#pragma unroll
    for (int i = 0; i < 4; ++i)
#pragma unroll
      for (int j = 0; j < 2; ++j)
#pragma unroll
        for (int ks = 0; ks < 2; ++ks)
          acc[4 + i][j] = __builtin_amdgcn_mfma_f32_16x16x32_bf16(
              afr[i][ks], bfr[j][ks], acc[4 + i][j], 0, 0, 0);
    __builtin_amdgcn_sched_barrier(0);
    __builtin_amdgcn_s_setprio(0);
    asm volatile("" ::: "memory");
    __builtin_amdgcn_s_barrier();
    asm volatile("" ::: "memory");

    // ---------------- phase 3: no reads; MFMA Q(1,1); counted vmcnt
    if (h0 + 3 < NH) stage(h0 + 3);
    asm volatile("" ::: "memory");
    __builtin_amdgcn_s_barrier();
    __builtin_amdgcn_sched_barrier(0);
    __builtin_amdgcn_s_setprio(1);
#pragma unroll
    for (int i = 0; i < 4; ++i)
#pragma unroll
      for (int j = 0; j < 2; ++j)
#pragma unroll
        for (int ks = 0; ks < 2; ++ks)
          acc[4 + i][2 + j] = __builtin_amdgcn_mfma_f32_16x16x32_bf16(
              afr[i][ks], bfr2[j][ks], acc[4 + i][2 + j], 0, 0, 0);
    __builtin_amdgcn_sched_barrier(0);
    __builtin_amdgcn_s_setprio(0);
    if (t < NT - 2) {
      asm volatile("s_waitcnt vmcnt(2)" ::: "memory");  // tile t+1 landed
    } else {
      asm volatile("s_waitcnt vmcnt(0)" ::: "memory");  // epilogue drain
    }
    __builtin_amdgcn_s_barrier();
    asm volatile("" ::: "memory");
  }

  // epilogue: C/D layout col=lane&15, row=quad*4+i  [verified m89/m91]
#pragma unroll
  for (int mt = 0; mt < 8; ++mt) {
    const size_t row0 = bm + wm + mt * 16 + quad * 4;
#pragma unroll
    for (int nt = 0; nt < 4; ++nt) {
      const size_t col = bn + wn + nt * 16 + l16;
      float* cp = C + row0 * N_DIM + col;
#pragma unroll
      for (int i = 0; i < 4; ++i)
        cp[(size_t)i * N_DIM] = acc[mt][nt][i];
    }
  }
}

// ------------------------------------------ fallback: fp32 tiled (insurance)
__global__ void gemm_f32_fallback(const float* __restrict__ A,
                                  const float* __restrict__ W,
                                  const float* __restrict__ Msk,
                                  float* __restrict__ C) {
  __shared__ float As[32][33];
  __shared__ float Bs[32][33];
  const int tx = threadIdx.x;
  const int ty = threadIdx.y;
  const size_t row0 = (size_t)blockIdx.y * 32;
  const size_t col0 = (size_t)blockIdx.x * 32;
  float acc[4] = {0.f, 0.f, 0.f, 0.f};
  for (int k0 = 0; k0 < K_DIM; k0 += 32) {
#pragma unroll
    for (int rr = 0; rr < 4; ++rr) {
      int rw = ty + rr * 8;
      As[rw][tx] = A[(row0 + rw) * K_DIM + k0 + tx];
      size_t gi = (size_t)(k0 + rw) * N_DIM + col0 + tx;
      Bs[rw][tx] = W[gi] * Msk[gi];
    }
    __syncthreads();
#pragma unroll
    for (int kk = 0; kk < 32; ++kk) {
      float b = Bs[kk][tx];
#pragma unroll
      for (int rr = 0; rr < 4; ++rr) acc[rr] += As[ty + rr * 8][kk] * b;
    }
    __syncthreads();
  }
#pragma unroll
  for (int rr = 0; rr < 4; ++rr)
    C[(row0 + ty + rr * 8) * N_DIM + col0 + tx] = acc[rr];
}

// ---------------------------------------------------------------- launcher
extern "C" void kernel_launch(void* const* d_in, const int* in_sizes, int n_in,
                              void* d_out, int out_size, void* d_ws,
                              size_t ws_size, hipStream_t stream) {
  const float* A   = (const float*)d_in[0];
  const float* W   = (const float*)d_in[1];
  const float* Msk = (const float*)d_in[2];
  float* C = (float*)d_out;

  const size_t bytesA = (size_t)M_DIM * K_DIM * sizeof(unsigned short);
  const size_t bytesB = (size_t)K_DIM * N_DIM * sizeof(unsigned short);

  if (ws_size >= bytesA + bytesB) {
    unsigned short* Abf = (unsigned short*)d_ws;
    unsigned short* Wt  = (unsigned short*)((char*)d_ws + bytesA);
    convert_a_kernel<<<dim3(((size_t)M_DIM * K_DIM) / 16 / 256), dim3(256), 0,
                       stream>>>(A, Abf);
    maskT_kernel<<<dim3(N_DIM / 64, K_DIM / 64), dim3(256), 0, stream>>>(
        W, Msk, Wt);
    gemm_bf16_kernel<<<dim3(N_DIM / BN, M_DIM / BM), dim3(512), 0, stream>>>(
        Abf, Wt, C);
  } else {
    gemm_f32_fallback<<<dim3(N_DIM / 32, M_DIM / 32), dim3(32, 8), 0,
                        stream>>>(A, W, Msk, C);
  }
}